// Round 1
// 140.282 us; speedup vs baseline: 1.0079x; 1.0079x over previous
//
#include <hip/hip_runtime.h>

#define PI_D 3.14159265358979323846

typedef __attribute__((ext_vector_type(8))) short bf16x8;
typedef __attribute__((ext_vector_type(4))) float f32x4;

static __device__ inline f32x4 mfma16(bf16x8 a, bf16x8 b, f32x4 c) {
    return __builtin_amdgcn_mfma_f32_16x16x32_bf16(a, b, c, 0, 0, 0);
}

static __device__ inline unsigned short f2bf(float f) {
    union { float f; unsigned u; } v; v.f = f;
    unsigned u = v.u;
    u += 0x7fffu + ((u >> 16) & 1u);   // RNE
    return (unsigned short)(u >> 16);
}
static __device__ inline float bf2f(unsigned short h) {
    union { unsigned u; float f; } v; v.u = ((unsigned)h) << 16;
    return v.f;
}

// load 8 consecutive f32 from global, convert to bf16x8 (RNE)
static __device__ inline bf16x8 ld_cvt8(const float* __restrict__ p) {
    float4 v0 = *(const float4*)p;
    float4 v1 = *(const float4*)(p + 4);
    bf16x8 r;
    r[0] = (short)f2bf(v0.x); r[1] = (short)f2bf(v0.y);
    r[2] = (short)f2bf(v0.z); r[3] = (short)f2bf(v0.w);
    r[4] = (short)f2bf(v1.x); r[5] = (short)f2bf(v1.y);
    r[6] = (short)f2bf(v1.z); r[7] = (short)f2bf(v1.w);
    return r;
}

// ---- ws float layout ----------------------------------------------------------------
#define OFF_TAB 0                         // 32768 bf16 = 16384 floats
#define OFF_WT3  16384                    // wt3[o][i][mode] cplx: 1024*512 float2 = 1,048,576 fl
#define OFF_XFR  (16384 + 1048576)        // 1024 bids x 512 modes f32 (re)
#define OFF_XFI  (OFF_XFR + 524288)       // (im)
// total = 2,113,536 floats ~ 8.45 MB

// table offsets in u16 units within OFF_TAB
#define TAB_E1 0        // [32 n=c*16+ky][128 w]
#define TAB_A2 4096     // [64 row=p*32+m][256 k=c*128+x]
#define TAB_A3 20480    // [128 x][64 k=c*32+m]
#define TAB_E4 28672    // [128 y][32 k=p*16+ky]

// ---------------- fused prep: tables (blocks 0..127) + weight relayout (128..1151) ----
__global__ __launch_bounds__(256) void k_prep(const float* __restrict__ wr,
                                              const float* __restrict__ wi,
                                              float* ws) {
    int blk = blockIdx.x, t = threadIdx.x;
    if (blk < 128) {
        int gid = blk * 256 + t;            // 0..32767
        unsigned short* tab = (unsigned short*)(ws + OFF_TAB);
        const float W128 = (float)(2.0 * PI_D / 128.0);
        if (gid < 4096) {                       // E1t: forward y-DFT, x(1/128) scale
            int n = gid >> 7, w = gid & 127;
            int ky = n & 15, c = n >> 4;
            float th = ((w * ky) & 127) * W128;
            float val = (c ? -sinf(th) : cosf(th)) * (1.f / 128.f);
            tab[TAB_E1 + gid] = f2bf(val);
        } else if (gid < 20480) {               // A2: forward x-DFT (complex-as-real)
            int idx = gid - 4096;
            int row = idx >> 8, k = idx & 255;
            int p = row >> 5, m = row & 31;
            int c = k >> 7, xx = k & 127;
            int kx = (m < 16) ? m : 96 + m;
            float th = ((xx * kx) & 127) * W128;
            float er = cosf(th), ei = -sinf(th);
            float val = (p == 0) ? (c == 0 ? er : -ei) : (c == 0 ? ei : er);
            tab[TAB_A2 + idx] = f2bf(val);
        } else if (gid < 28672) {               // A3: inverse x-DFT
            int idx = gid - 20480;
            int xx = idx >> 6, k = idx & 63;
            int c = k >> 5, m = k & 31;
            int kx = (m < 16) ? m : 96 + m;
            float th = ((xx * kx) & 127) * W128;
            float er = cosf(th), ei = sinf(th);
            float val = (c == 0) ? er : -ei;
            tab[TAB_A3 + idx] = f2bf(val);
        } else {                                // E4t: inverse y-DFT w/ hermitian weights
            int idx = gid - 28672;
            int y = idx >> 5, k = idx & 31;
            int p = k >> 4, ky = k & 15;
            float th = ((y * ky) & 127) * W128;
            float sc = (ky == 0 ? 1.f : 2.f) / 128.f;
            float val = (p == 0) ? sc * cosf(th) : -sc * sinf(th);
            tab[TAB_E4 + idx] = f2bf(val);
        }
    } else {
        int bid = blk - 128;             // o*32 + i
        int o = bid >> 5, i = bid & 31;
        const float* r  = wr + (size_t)(i * 32 + o) * 512;
        const float* im = wi + (size_t)(i * 32 + o) * 512;
        float2* dst = (float2*)(ws + OFF_WT3) + (size_t)bid * 512;
        dst[t]       = make_float2(r[t],       im[t]);
        dst[t + 256] = make_float2(r[t + 256], im[t + 256]);
    }
}

// ---------------- forward: x[bid,:,:] --MFMA--> xfr/xfi[bid][mode] --------------------
// X fragments loaded DIRECTLY from global (each x element feeds exactly one fragment
// lane -> LDS staging had zero reuse). E1 read from the L1-hot global table.
__global__ __launch_bounds__(256) void k_f(const float* __restrict__ x, float* ws) {
    __shared__ __align__(16) unsigned short Yl[16 * 264];    // Y: [ky][k=c*128+x]
    int t = threadIdx.x, bid = blockIdx.x;
    const unsigned short* tab = (const unsigned short*)(ws + OFF_TAB);
    int lid = t & 15, q = (t >> 4) & 3, w = t >> 6;
    const float* xim = x + (size_t)bid * 16384;

    // F1: C[x][(c,ky)] = sum_w X[x][w] E1t[(c,ky)][w];  M=128 N=32 K=128
    f32x4 acc[2][2] = {};
#pragma unroll
    for (int ks = 0; ks < 4; ++ks) {
        bf16x8 a0 = ld_cvt8(xim + (32 * w + lid) * 128 + ks * 32 + q * 8);
        bf16x8 a1 = ld_cvt8(xim + (32 * w + 16 + lid) * 128 + ks * 32 + q * 8);
        bf16x8 b0 = *(const bf16x8*)&tab[TAB_E1 + lid * 128 + ks * 32 + q * 8];
        bf16x8 b1 = *(const bf16x8*)&tab[TAB_E1 + (16 + lid) * 128 + ks * 32 + q * 8];
        acc[0][0] = mfma16(a0, b0, acc[0][0]);
        acc[0][1] = mfma16(a0, b1, acc[0][1]);
        acc[1][0] = mfma16(a1, b0, acc[1][0]);
        acc[1][1] = mfma16(a1, b1, acc[1][1]);
    }
    // epilogue: Y -> Yl[ky][c*128+x] bf16
#pragma unroll
    for (int mt = 0; mt < 2; ++mt)
#pragma unroll
        for (int nt = 0; nt < 2; ++nt) {
            ushort4 h;
            h.x = f2bf(acc[mt][nt][0]); h.y = f2bf(acc[mt][nt][1]);
            h.z = f2bf(acc[mt][nt][2]); h.w = f2bf(acc[mt][nt][3]);
            *(ushort4*)&Yl[lid * 264 + nt * 128 + 32 * w + mt * 16 + q * 4] = h;
        }
    __syncthreads();

    // F2: C[(p,m)][ky] = sum_k A2[(p,m)][k] Yl[ky][k];  M=64 N=16 K=256
    f32x4 acc2 = {};
    const unsigned short* A2g = tab + TAB_A2;
#pragma unroll
    for (int ks = 0; ks < 8; ++ks) {
        bf16x8 a = *(const bf16x8*)&A2g[(16 * w + lid) * 256 + ks * 32 + q * 8];
        bf16x8 b = *(const bf16x8*)&Yl[lid * 264 + ks * 32 + q * 8];
        acc2 = mfma16(a, b, acc2);
    }
    int p = w >> 1, mb = (w & 1) * 16;
    float* xfp = ws + (p ? OFF_XFI : OFF_XFR) + (size_t)bid * 512;
#pragma unroll
    for (int r = 0; r < 4; ++r)
        xfp[(mb + q * 4 + r) * 16 + lid] = acc2[r];
}

// ---------------- fused mix + inverse: block (b,o) -> out[b,o,:,:] --------------------
// Split-bf16 (hi+lo) for Bl and Zl. A3/E4 tables read directly from global (L1-hot):
// LDS 62.5KB -> 33KB => 4 blocks/CU, doubling latency-hiding for the mix loop.
__global__ __launch_bounds__(256) void k_im(const float* __restrict__ ws, float* __restrict__ out) {
    __shared__ __align__(16) unsigned short Zlh[128 * 40];   // [x][k=p*16+ky] hi
    __shared__ __align__(16) unsigned short Zll[128 * 40];   // lo residual
    __shared__ __align__(16) unsigned short Blh[32 * 72];    // [(p,ky)][k=c*32+m] hi
    __shared__ __align__(16) unsigned short Bll[32 * 72];    // lo residual
    __shared__ float2 zm[512];
    int t = threadIdx.x, bid = blockIdx.x;                   // b*32 + o
    int b = bid >> 5, o = bid & 31;
    const unsigned short* tab = (const unsigned short*)(ws + OFF_TAB);

    // ---- channel mix, f32: zm[mode] = sum_i xf[b,i,mode] * w3[o,i,mode]
    {
        const float* xfr = ws + OFF_XFR;
        const float* xfi = ws + OFF_XFI;
        const float* w3  = ws + OFF_WT3;     // float2[(o*32+i)*512 + mode]
        float a0r = 0.f, a0i = 0.f, a1r = 0.f, a1i = 0.f;
#pragma unroll 4
        for (int i = 0; i < 32; ++i) {
            const float2 xr2 = *(const float2*)(xfr + (size_t)(b * 32 + i) * 512 + 2 * t);
            const float2 xi2 = *(const float2*)(xfi + (size_t)(b * 32 + i) * 512 + 2 * t);
            const float4 w4  = *(const float4*)(w3 + ((size_t)(o * 32 + i) * 512 + 2 * t) * 2);
            a0r = fmaf(xr2.x, w4.x, fmaf(-xi2.x, w4.y, a0r));
            a0i = fmaf(xr2.x, w4.y, fmaf( xi2.x, w4.x, a0i));
            a1r = fmaf(xr2.y, w4.z, fmaf(-xi2.y, w4.w, a1r));
            a1i = fmaf(xr2.y, w4.w, fmaf( xi2.y, w4.z, a1i));
        }
        zm[2 * t]     = make_float2(a0r, a0i);
        zm[2 * t + 1] = make_float2(a1r, a1i);
    }
    __syncthreads();

    // build Blh/Bll from zm (complex-as-real with sign trick; hi + residual-lo)
    {
        int n = t >> 3, k0 = (t & 7) * 8;
        int p = n >> 4, ky = n & 15;
        unsigned short hh[8], hl[8];
#pragma unroll
        for (int j = 0; j < 8; ++j) {
            int k = k0 + j, c = k >> 5, m = k & 31;
            float2 v = zm[m * 16 + ky];
            float val = (p == 0) ? (c == 0 ? v.x : v.y) : (c == 0 ? v.y : -v.x);
            unsigned short vh = f2bf(val);
            hh[j] = vh;
            hl[j] = f2bf(val - bf2f(vh));
        }
        ushort4 a, bb;
        a.x = hh[0]; a.y = hh[1]; a.z = hh[2]; a.w = hh[3];
        bb.x = hh[4]; bb.y = hh[5]; bb.z = hh[6]; bb.w = hh[7];
        *(ushort4*)&Blh[n * 72 + k0]     = a;
        *(ushort4*)&Blh[n * 72 + k0 + 4] = bb;
        a.x = hl[0]; a.y = hl[1]; a.z = hl[2]; a.w = hl[3];
        bb.x = hl[4]; bb.y = hl[5]; bb.z = hl[6]; bb.w = hl[7];
        *(ushort4*)&Bll[n * 72 + k0]     = a;
        *(ushort4*)&Bll[n * 72 + k0 + 4] = bb;
    }
    __syncthreads();

    int lid = t & 15, q = (t >> 4) & 3, w = t >> 6;

    // I1: Z[x][(p,ky)] = sum_k A3[x][k] (Bh+Bl)[(p,ky)][k];  M=128 N=32 K=64, double-pumped
    f32x4 acc[2][2] = {};
#pragma unroll
    for (int ks = 0; ks < 2; ++ks) {
        bf16x8 a0  = *(const bf16x8*)&tab[TAB_A3 + (32 * w + lid) * 64 + ks * 32 + q * 8];
        bf16x8 a1  = *(const bf16x8*)&tab[TAB_A3 + (32 * w + 16 + lid) * 64 + ks * 32 + q * 8];
        bf16x8 bh0 = *(const bf16x8*)&Blh[lid * 72 + ks * 32 + q * 8];
        bf16x8 bh1 = *(const bf16x8*)&Blh[(16 + lid) * 72 + ks * 32 + q * 8];
        bf16x8 bl0 = *(const bf16x8*)&Bll[lid * 72 + ks * 32 + q * 8];
        bf16x8 bl1 = *(const bf16x8*)&Bll[(16 + lid) * 72 + ks * 32 + q * 8];
        acc[0][0] = mfma16(a0, bl0, acc[0][0]);
        acc[0][0] = mfma16(a0, bh0, acc[0][0]);
        acc[0][1] = mfma16(a0, bl1, acc[0][1]);
        acc[0][1] = mfma16(a0, bh1, acc[0][1]);
        acc[1][0] = mfma16(a1, bl0, acc[1][0]);
        acc[1][0] = mfma16(a1, bh0, acc[1][0]);
        acc[1][1] = mfma16(a1, bl1, acc[1][1]);
        acc[1][1] = mfma16(a1, bh1, acc[1][1]);
    }
    // epilogue: Z -> Zlh/Zll[x][p*16+ky] (hi + residual-lo)
#pragma unroll
    for (int mt = 0; mt < 2; ++mt)
#pragma unroll
        for (int nt = 0; nt < 2; ++nt)
#pragma unroll
            for (int r = 0; r < 4; ++r) {
                float z = acc[mt][nt][r];
                unsigned short zh = f2bf(z);
                int idx = (32 * w + mt * 16 + q * 4 + r) * 40 + nt * 16 + lid;
                Zlh[idx] = zh;
                Zll[idx] = f2bf(z - bf2f(zh));
            }
    __syncthreads();

    // I2: out[x][y] = sum_k (Zh+Zl)[x][k] E4t[y][k];  M=128 N=128 K=32, double-pumped
    f32x4 acc2[2][8];
#pragma unroll
    for (int mt = 0; mt < 2; ++mt) {
        bf16x8 ah = *(const bf16x8*)&Zlh[(32 * w + mt * 16 + lid) * 40 + q * 8];
        bf16x8 al = *(const bf16x8*)&Zll[(32 * w + mt * 16 + lid) * 40 + q * 8];
#pragma unroll
        for (int nt = 0; nt < 8; ++nt) {
            bf16x8 bb = *(const bf16x8*)&tab[TAB_E4 + (nt * 16 + lid) * 32 + q * 8];
            f32x4 z = {};
            z = mfma16(al, bb, z);
            acc2[mt][nt] = mfma16(ah, bb, z);
        }
    }
    float* og = out + (size_t)bid * 16384;
#pragma unroll
    for (int mt = 0; mt < 2; ++mt)
#pragma unroll
        for (int r = 0; r < 4; ++r)
#pragma unroll
            for (int nt = 0; nt < 8; ++nt)
                og[(32 * w + mt * 16 + q * 4 + r) * 128 + nt * 16 + lid] = acc2[mt][nt][r];
}

extern "C" void kernel_launch(void* const* d_in, const int* in_sizes, int n_in,
                              void* d_out, int out_size, void* d_ws, size_t ws_size,
                              hipStream_t stream) {
    const float* x  = (const float*)d_in[0];
    const float* wr = (const float*)d_in[1];
    const float* wi = (const float*)d_in[2];
    float* out = (float*)d_out;
    float* ws  = (float*)d_ws;
    k_prep<<<dim3(1152), dim3(256), 0, stream>>>(wr, wi, ws);
    k_f   <<<dim3(1024), dim3(256), 0, stream>>>(x, ws);
    k_im  <<<dim3(1024), dim3(256), 0, stream>>>(ws, out);
}